// Round 6
// baseline (17.983 us; speedup 1.0000x reference)
//
#include <hip/hip_runtime.h>

#define WORD_LEN 16
#define BLOCK 256
#define WPT 2   // words per thread: software pipeline depth

// Per-word scan. All indices compile-time (full unroll) -> registers only.
__device__ __forceinline__ void process_word(
    const float4* __restrict__ slo, const float4* __restrict__ shi,
    int4 w0, int4 w1, int4 w2, int4 w3, float* __restrict__ o)
{
    const int id[16] = {w0.x, w0.y, w0.z, w0.w,  w1.x, w1.y, w1.z, w1.w,
                        w2.x, w2.y, w2.z, w2.w,  w3.x, w3.y, w3.z, w3.w};

    float v0, v1, v2, v3, v4, v5, v6;
    {
        const float4 a = slo[id[0]];
        const float4 h = shi[id[0]];
        v0 = a.x; v1 = a.y; v2 = a.z; v3 = a.w;
        v4 = h.x; v5 = h.y; v6 = h.z;
    }

    #pragma unroll
    for (int t = 1; t < WORD_LEN; ++t) {
        const float4 a = shi ? slo[id[t]] : a;  // (no-op guard removed below)
        const float4 aa = slo[id[t]];
        const float4 hh = shi[id[t]];
        const float x0 = aa.x, x1 = aa.y, x2 = aa.z, x3 = aa.w;
        const float x4 = hh.x, x5 = hh.y, x6 = hh.z;

        // Fano-plane 7D cross, per-component: 1 mul + 5 fma each (no zero-init
        // movs; fma-into-+0 is not foldable without fast-math).
        float r0 = v1 * x2;  r0 = fmaf(-v2, x1, r0);  r0 = fmaf(v3, x4, r0);
        r0 = fmaf(-v4, x3, r0);  r0 = fmaf(v6, x5, r0);  r0 = fmaf(-v5, x6, r0);
        float r1 = v2 * x0;  r1 = fmaf(-v0, x2, r1);  r1 = fmaf(v3, x5, r1);
        r1 = fmaf(-v5, x3, r1);  r1 = fmaf(v4, x6, r1);  r1 = fmaf(-v6, x4, r1);
        float r2 = v0 * x1;  r2 = fmaf(-v1, x0, r2);  r2 = fmaf(v3, x6, r2);
        r2 = fmaf(-v6, x3, r2);  r2 = fmaf(v5, x4, r2);  r2 = fmaf(-v4, x5, r2);
        float r3 = v4 * x0;  r3 = fmaf(-v0, x4, r3);  r3 = fmaf(v5, x1, r3);
        r3 = fmaf(-v1, x5, r3);  r3 = fmaf(v6, x2, r3);  r3 = fmaf(-v2, x6, r3);
        float r4 = v0 * x3;  r4 = fmaf(-v3, x0, r4);  r4 = fmaf(v6, x1, r4);
        r4 = fmaf(-v1, x6, r4);  r4 = fmaf(v2, x5, r4);  r4 = fmaf(-v5, x2, r4);
        float r5 = v0 * x6;  r5 = fmaf(-v6, x0, r5);  r5 = fmaf(v1, x3, r5);
        r5 = fmaf(-v3, x1, r5);  r5 = fmaf(v4, x2, r5);  r5 = fmaf(-v2, x4, r5);
        float r6 = v5 * x0;  r6 = fmaf(-v0, x5, r6);  r6 = fmaf(v1, x4, r6);
        r6 = fmaf(-v4, x1, r6);  r6 = fmaf(v2, x3, r6);  r6 = fmaf(-v3, x2, r6);

        v0 = r0; v1 = r1; v2 = r2; v3 = r3; v4 = r4; v5 = r5; v6 = r6;
    }

    o[0] = v0; o[1] = v1; o[2] = v2; o[3] = v3; o[4] = v4; o[5] = v5; o[6] = v6;
}

// (256, 4): 4 blocks/CU -> 4 waves/SIMD, VGPR cap 128 (live state ~70).
__global__ __launch_bounds__(BLOCK, 4) void oct_word_emb_kernel(
    const int* __restrict__ ids,
    const float* __restrict__ emb,
    float* __restrict__ out)
{
    // Embedding imag parts, 16B rows: 2x ds_read_b128 per char (round-4 win).
    __shared__ float4 slo[256];   // imag 1..4
    __shared__ float4 shi[256];   // imag 5..7 + pad

    const int tid = threadIdx.x;
    {
        const float4* e4 = reinterpret_cast<const float4*>(emb);
        float4 lo = e4[tid * 2 + 0];
        float4 hi = e4[tid * 2 + 1];
        slo[tid] = make_float4(lo.y, lo.z, lo.w, hi.x);
        shi[tid] = make_float4(hi.y, hi.z, hi.w, 0.0f);
    }
    __syncthreads();

    // Two words per thread: word A = base+tid, word B = base+256+tid.
    // All 8 id loads issued up-front; word B's loads fly under word A's
    // compute, word A's stores retire under word B's compute.
    const size_t wbase = (size_t)blockIdx.x * (BLOCK * WPT);
    const size_t wa = wbase + tid;
    const size_t wb = wbase + BLOCK + tid;

    const int4* ga = reinterpret_cast<const int4*>(ids) + wa * 4;
    const int4* gb = reinterpret_cast<const int4*>(ids) + wb * 4;
    const int4 a0 = ga[0], a1 = ga[1], a2 = ga[2], a3 = ga[3];
    const int4 b0 = gb[0], b1 = gb[1], b2 = gb[2], b3 = gb[3];

    process_word(slo, shi, a0, a1, a2, a3, out + wa * 7);
    process_word(slo, shi, b0, b1, b2, b3, out + wb * 7);
}

extern "C" void kernel_launch(void* const* d_in, const int* in_sizes, int n_in,
                              void* d_out, int out_size, void* d_ws, size_t ws_size,
                              hipStream_t stream) {
    const int* ids = (const int*)d_in[0];      // (524288, 16) int32
    const float* emb = (const float*)d_in[1];  // (256, 8) fp32
    float* out = (float*)d_out;                // (524288, 7) fp32

    const int batch = in_sizes[0] / WORD_LEN;  // 524288
    const int grid = batch / (BLOCK * WPT);    // 1024

    oct_word_emb_kernel<<<grid, BLOCK, 0, stream>>>(ids, emb, out);
}